// Round 13
// baseline (522.770 us; speedup 1.0000x reference)
//
#include <hip/hip_runtime.h>
#include <hip/hip_bf16.h>
#include <hip/hip_fp16.h>
#include <math.h>

// ---------------------------------------------------------------------------
// Diffusion renoise-loop + conditional MLP loss, MI355X (gfx950).
// RNG: threefry_partitionable (bit-exact, absmax 0.0 rounds 1-13, 15-17, 19-23).
// Round 24: r23 confirmed fused-reduce correct but neutral; tail is harness-
// fixed. Only lever with evidence: r21's pass-halving (8->4 passes, -9%).
// Iterate it: 4 states/pass, 2 passes -> 32 serial ctc-steps (from 64).
// Pass 0 sweeps states 0-3 for all points (16 MFMA chains/cc = 2x ILP);
// pass 1 handles the ~1/16 survivors (nbq=1 or full break). Pure pair->quad
// generalization of r21's verified machinery (znyS0..3, bq0..3, dvv0..3,
// 16 wave-uniform masks, 4-way first-clear-bit mp update).
#define BS   128
#define NS   1024
#define HID  512
#define CTX  128
#define TT   100
#define ITERS 8

// ---- workspace layout (bytes) ---------------------------------------------
constexpr size_t OFF_SACP  = 0;         // 100 f32
constexpr size_t OFF_S1M   = 512;       // 100 f32
constexpr size_t OFF_KEYS  = 1024;      // 16 u32
constexpr size_t OFF_CNTG  = 1152;      // u32[8][512] -> 17536
constexpr size_t OFF_DONE  = 17536;     // u32 done counter
constexpr size_t OFF_MASK  = 33920;     // u8[131072] -> 164992
constexpr size_t OFF_BIAS  = 262144;    // f32[128*512] -> 524288
constexpr size_t OFF_PA    = 524288;    // float4[512] -> 532480
constexpr size_t OFF_PB    = 532480;    // float4[512] -> 540672
constexpr size_t OFF_PC    = 540672;    // f32[512]   -> 542720
constexpr size_t OFF_PART  = 542720;    // f32[512]   -> 544768 (~0.55 MB)

typedef __attribute__((ext_vector_type(8))) _Float16 half8;
typedef __attribute__((ext_vector_type(4))) float f32x4;

// ---- threefry2x32-20 -------------------------------------------------------
__device__ __forceinline__ unsigned rotl32(unsigned x, int r) {
  return (x << r) | (x >> (32 - r));
}
__device__ __forceinline__ void tf2x32(unsigned k0, unsigned k1,
                                       unsigned x0, unsigned x1,
                                       unsigned& o0, unsigned& o1) {
  unsigned k2 = k0 ^ k1 ^ 0x1BD11BDAu;
  x0 += k0; x1 += k1;
#define TF_R4(a,b,c,d) \
  x0 += x1; x1 = rotl32(x1,(a)); x1 ^= x0; \
  x0 += x1; x1 = rotl32(x1,(b)); x1 ^= x0; \
  x0 += x1; x1 = rotl32(x1,(c)); x1 ^= x0; \
  x0 += x1; x1 = rotl32(x1,(d)); x1 ^= x0;
  TF_R4(13,15,26,6)   x0 += k1; x1 += k2 + 1u;
  TF_R4(17,29,16,24)  x0 += k2; x1 += k0 + 2u;
  TF_R4(13,15,26,6)   x0 += k0; x1 += k1 + 3u;
  TF_R4(17,29,16,24)  x0 += k1; x1 += k2 + 4u;
  TF_R4(13,15,26,6)   x0 += k2; x1 += k0 + 5u;
#undef TF_R4
  o0 = x0; o1 = x1;
}

__device__ __forceinline__ float bits_to_u(unsigned bits) {
  float f = __uint_as_float((bits >> 9) | 0x3f800000u) - 1.0f;
  float u = f * 2.0f + (-0.99999994f);
  return fmaxf(-0.99999994f, u);
}

__device__ __forceinline__ float nrm_from_idx(unsigned k0, unsigned k1, unsigned idx) {
  unsigned o0, o1;
  tf2x32(k0, k1, 0u, idx, o0, o1);
  return 1.41421356f * erfinvf(bits_to_u(o0 ^ o1));
}

__device__ __forceinline__ float ftanh(float x) {
  float e = __expf(2.0f * x);
  float r = __builtin_amdgcn_rcpf(e + 1.0f);
  return fmaf(-2.0f, r, 1.0f);
}

// fp16 hi/lo split: x ~= hi + lo with |err| <~ 2^-23 |x|
__device__ __forceinline__ void split16(float x, unsigned short& hi, unsigned short& lo) {
  __half h = __float2half(x);
  float hf = __half2float(h);
  __half l = __float2half(x - hf);
  hi = __half_as_ushort(h);
  lo = __half_as_ushort(l);
}
__device__ __forceinline__ unsigned pack2(unsigned short a, unsigned short b) {
  return (unsigned)a | ((unsigned)b << 16);
}
// duplicate low/high 16-bit half of u into both halves (1 v_perm_b32 each)
__device__ __forceinline__ unsigned dup_lo(unsigned u) {
  return __builtin_amdgcn_perm(u, u, 0x01000100u);  // bytes [0,1,0,1]
}
__device__ __forceinline__ unsigned dup_hi(unsigned u) {
  return __builtin_amdgcn_perm(u, u, 0x03020302u);  // bytes [2,3,2,3]
}

// pack one pre-split word + row-shared data words into a B-operand vector
__device__ __forceinline__ half8 mk_bq(int quad, unsigned shared_x,
                                       unsigned shared_y, unsigned zw0,
                                       unsigned zw1, unsigned zw2) {
  // quad0: shared = data dims 0,1 (wds from shared_x, shared_y)
  // quad1: x,y from shared (dim2); z,w from zw0 (noisy dim3)
  // quad2: from zw1 (dim4), zw2 (dim5); quad3: ones
  uint4 wds = make_uint4(0u, 0u, 0u, 0u);
  if (quad == 0) {
    wds.x = dup_lo(shared_x); wds.y = dup_hi(shared_x);
    wds.z = dup_lo(shared_y); wds.w = dup_hi(shared_y);
  } else if (quad == 1) {
    wds.x = dup_lo(shared_x); wds.y = dup_hi(shared_x);
    wds.z = dup_lo(zw0); wds.w = dup_hi(zw0);
  } else if (quad == 2) {
    wds.x = dup_lo(zw1); wds.y = dup_hi(zw1);
    wds.z = dup_lo(zw2); wds.w = dup_hi(zw2);
  } else {
    wds.x = 0x3C003C00u;
  }
  return __builtin_bit_cast(half8, wds);
}

// ---- quad-state candidate sweep: NBQ tiles x 4 states over 64 cand tiles ---
template<int NBQ>
__device__ __forceinline__ void sweepQ(const unsigned* stw, int abase,
                                       const half8* bq0, const half8* bq1,
                                       const half8* bq2, const half8* bq3,
                                       float* bv0, float* bv1,
                                       float* bv2, float* bv3) {
#pragma unroll
  for (int k = 0; k < NBQ; ++k) {
    bv0[k] = -__builtin_inff(); bv1[k] = -__builtin_inff();
    bv2[k] = -__builtin_inff(); bv3[k] = -__builtin_inff();
  }
  uint2 cu[4], cun[4];
#pragma unroll
  for (int cc = 0; cc < 4; ++cc)
    cu[cc] = *(const uint2*)(stw + cc * 128 + abase);
#pragma unroll 1
  for (int ctc = 0; ctc < 16; ++ctc) {
    if (ctc < 15) {
#pragma unroll
      for (int cc = 0; cc < 4; ++cc)
        cun[cc] = *(const uint2*)(stw + ((ctc + 1) * 4 + cc) * 128 + abase);
    }
#pragma unroll
    for (int cc = 0; cc < 4; ++cc) {
      half8 ac = __builtin_bit_cast(half8,
                   make_uint4(cu[cc].x, cu[cc].x, cu[cc].y, cu[cc].y));
      f32x4 z = {0.f, 0.f, 0.f, 0.f};
#pragma unroll
      for (int k = 0; k < NBQ; ++k) {
        f32x4 a0 = __builtin_amdgcn_mfma_f32_16x16x32_f16(ac, bq0[k], z, 0, 0, 0);
        f32x4 a1 = __builtin_amdgcn_mfma_f32_16x16x32_f16(ac, bq1[k], z, 0, 0, 0);
        f32x4 a2 = __builtin_amdgcn_mfma_f32_16x16x32_f16(ac, bq2[k], z, 0, 0, 0);
        f32x4 a3 = __builtin_amdgcn_mfma_f32_16x16x32_f16(ac, bq3[k], z, 0, 0, 0);
        bv0[k] = fmaxf(fmaxf(bv0[k], fmaxf(fmaxf(a0[0], a0[1]), a0[2])), a0[3]);
        bv1[k] = fmaxf(fmaxf(bv1[k], fmaxf(fmaxf(a1[0], a1[1]), a1[2])), a1[3]);
        bv2[k] = fmaxf(fmaxf(bv2[k], fmaxf(fmaxf(a2[0], a2[1]), a2[2])), a2[3]);
        bv3[k] = fmaxf(fmaxf(bv3[k], fmaxf(fmaxf(a3[0], a3[1]), a3[2])), a3[3]);
      }
    }
    if (ctc < 15) {
#pragma unroll
      for (int cc = 0; cc < 4; ++cc) cu[cc] = cun[cc];
    }
  }
}

// ---- kernel 1: setup — blocks 0..255 bias, 256 weight pack, 257 tables -----
__global__ __launch_bounds__(256) void k_setup(
    const float* __restrict__ ctx, const float* __restrict__ Wc,
    const float* __restrict__ Wt, const float* __restrict__ b1,
    const int* __restrict__ ts, float* __restrict__ biasb,
    const float* __restrict__ W1, const float* __restrict__ W2,
    float4* __restrict__ PA, float4* __restrict__ PB, float* __restrict__ PC,
    float* __restrict__ sacp, float* __restrict__ s1m,
    unsigned* __restrict__ keys, unsigned* __restrict__ done) {
  if (blockIdx.x == 257) {
    __shared__ double omb[TT];
    int t = threadIdx.x;
    if (t == 0) done[0] = 0u;   // replay-safe reset for k_loss last-block
    if (t < TT) {
      const double PI = 3.14159265358979323846;
      double t0 = (double)t / TT, t1 = (double)(t + 1) / TT;
      double c0 = cos((t0 + 0.008) / 1.008 * PI * 0.5); double ab0 = c0 * c0;
      double c1 = cos((t1 + 0.008) / 1.008 * PI * 0.5); double ab1 = c1 * c1;
      double beta = 1.0 - ab1 / ab0;
      if (beta > 0.999) beta = 0.999;
      omb[t] = 1.0 - beta;
    }
    __syncthreads();
    if (t < TT) {
      double acp = 1.0;
      for (int i = 0; i <= t; ++i) acp *= omb[i];
      sacp[t] = (float)sqrt(acp);
      s1m[t]  = (float)sqrt(1.0 - acp);
    }
    if (t >= 128 && t < 128 + ITERS) {
      int k = t - 128;
      unsigned o0, o1;
      tf2x32(0u, 42u, 0u, (unsigned)k, o0, o1);
      keys[2*k] = o0; keys[2*k+1] = o1;
    }
    return;
  }
  if (blockIdx.x == 256) {
    for (int j = threadIdx.x; j < HID; j += 256) {
      PA[j] = make_float4(W1[j], W1[512 + j], W1[1024 + j], W1[1536 + j]);
      PB[j] = make_float4(W1[2048 + j], W1[2560 + j], W2[j*6 + 3], W2[j*6 + 4]);
      PC[j] = W2[j*6 + 5];
    }
    return;
  }
  __shared__ float sc[CTX];
  int b = blockIdx.x >> 1;
  int j = (blockIdx.x & 1) * 256 + (int)threadIdx.x;
  if (threadIdx.x < CTX) sc[threadIdx.x] = ctx[(size_t)b * CTX + threadIdx.x];
  __syncthreads();
  float acc = 0.f;
  for (int q = 0; q < CTX; ++q) acc = fmaf(sc[q], Wc[q * HID + j], acc);
  float temb = (float)ts[b] / 100.0f;
  biasb[b * HID + j] = acc + temb * Wt[j] + b1[j];
}

// ---- kernel 2: renoise — 512 blocks (4 q-slices x 128 batches) -------------
// Wave-autonomous QUAD-state passes with point compaction. Pass j (states
// 4j..4j+3): ballot+mbcnt compacts unmatched into znyS0..3 slots; nbq tiles;
// sweepQ<nbq> evaluates 4 states; mp = first clear bit. No barriers in loop.
__global__ __launch_bounds__(256, 2) void k_renoise(
    const float* __restrict__ data, const float* __restrict__ noise0,
    const int* __restrict__ ts, const float* __restrict__ sacp,
    const float* __restrict__ s1m, const unsigned* __restrict__ keys,
    unsigned* __restrict__ cntg, unsigned char* __restrict__ maskg) {
  __shared__ unsigned stw[8192];           // 32 KB: 1024 rec x 8 words (r17)
  __shared__ uint4 znyS0[4][64];           // 4 KB: [wave][slot] s0 words+row
  __shared__ uint4 znyS1[4][64];           // 4 KB
  __shared__ uint4 znyS2[4][64];           // 4 KB
  __shared__ uint4 znyS3[4][64];           // 4 KB
  __shared__ unsigned cnt[8];
  const int b = blockIdx.x & 127, qb = blockIdx.x >> 7;  // qb 0..3
  const int tid = (int)threadIdx.x;
  const int wv = tid >> 6, lane = tid & 63;
  const int c15 = lane & 15, quad = lane >> 4;
  const int n0 = qb * 256;
  const int t = ts[b];
  const float aa = sacp[t], ssv = s1m[t];
  if (tid < ITERS) cnt[tid] = 0u;
  // ---- stage full panel: 4 rows/thread, swizzled pair stores (r17) ---------
#pragma unroll 1
  for (int ii = 0; ii < 4; ++ii) {
    int c = ii * 256 + tid;
    const float2* dp2 = (const float2*)(data + ((size_t)(b << 10) + c) * 6);
    float2 v0 = dp2[0], v1 = dp2[1], v2 = dp2[2];
    float dd[6] = {v0.x, v0.y, v1.x, v1.y, v2.x, v2.y};
    float dsq = dd[0]*dd[0];
    dsq = fmaf(dd[1], dd[1], dsq); dsq = fmaf(dd[2], dd[2], dsq);
    dsq = fmaf(dd[3], dd[3], dsq); dsq = fmaf(dd[4], dd[4], dsq);
    dsq = fmaf(dd[5], dd[5], dsq);
    unsigned U[6];
#pragma unroll
    for (int d = 0; d < 6; ++d) {
      unsigned short hi, lo; split16(dd[d], hi, lo);
      U[d] = pack2(hi, lo);
    }
    unsigned short vh, vl; split16(-0.5f * dsq, vh, vl);
    int sc_ = (c >> 2) & 3;
    unsigned* rec = stw + c * 8;
    *(uint2*)(rec + 2 * (0 ^ sc_)) = make_uint2(U[0], U[1]);
    *(uint2*)(rec + 2 * (1 ^ sc_)) = make_uint2(U[2], U[3]);
    *(uint2*)(rec + 2 * (2 ^ sc_)) = make_uint2(U[4], U[5]);
    *(uint2*)(rec + 2 * (3 ^ sc_)) = make_uint2(pack2(vh, vl), 0u);
  }
  // candidate A-gather base: rows cc*16+c15 -> (row>>2)&3 == c15>>2
  const int abase = c15 * 8 + 2 * (quad ^ (c15 >> 2));
  __syncthreads();
  // ---- per-lane persistent state -------------------------------------------
  const int qrow = n0 + wv * 64 + lane;    // row within batch panel (0..1023)
  const int pg = (b << 10) + qrow;         // global point index
  const float* dpq = data + (size_t)pg * 6;
  const float d3 = dpq[3], d4 = dpq[4], d5 = dpq[5];
  int mpv = 8;
  int myslot = 0;
  // ---- wave-autonomous quad-state passes -----------------------------------
#pragma unroll 1
  for (int j = 0; j < 2; ++j) {
    const int s0 = 4 * j;
    bool unm = (mpv == 8);
    unsigned long long mask = __ballot(unm ? 1 : 0);
    if (mask == 0ull) break;               // wave done; SIMD freed
    int nUnm = (int)__popcll(mask);
    int nbq = (nUnm + 15) >> 4;            // 1..4 query tiles
    if (unm) {
      unsigned base6 = (unsigned)pg * 6u;
      // state s0+0: noise0 (j==0) or keys pair s0-1
      float z3a, z4a, z5a;
      if (j == 0) {
        const float* np0 = noise0 + (size_t)pg * 6;
        z3a = np0[3]; z4a = np0[4]; z5a = np0[5];
      } else {
        unsigned ka0 = keys[2*(s0-1)], ka1 = keys[2*(s0-1)+1];
        z3a = nrm_from_idx(ka0, ka1, base6 + 3u);
        z4a = nrm_from_idx(ka0, ka1, base6 + 4u);
        z5a = nrm_from_idx(ka0, ka1, base6 + 5u);
      }
      // states s0+1..s0+3: keys pairs s0, s0+1, s0+2
      unsigned kb0 = keys[2*s0],     kb1 = keys[2*s0+1];
      unsigned kc0 = keys[2*(s0+1)], kc1 = keys[2*(s0+1)+1];
      unsigned kd0 = keys[2*(s0+2)], kd1 = keys[2*(s0+2)+1];
      float z3b = nrm_from_idx(kb0, kb1, base6 + 3u);
      float z4b = nrm_from_idx(kb0, kb1, base6 + 4u);
      float z5b = nrm_from_idx(kb0, kb1, base6 + 5u);
      float z3c = nrm_from_idx(kc0, kc1, base6 + 3u);
      float z4c = nrm_from_idx(kc0, kc1, base6 + 4u);
      float z5c = nrm_from_idx(kc0, kc1, base6 + 5u);
      float z3d = nrm_from_idx(kd0, kd1, base6 + 3u);
      float z4d = nrm_from_idx(kd0, kd1, base6 + 4u);
      float z5d = nrm_from_idx(kd0, kd1, base6 + 5u);
      unsigned short h_, l_;
      unsigned wa0, wa1, wa2, wb0, wb1, wb2, wc0, wc1, wc2, wd0, wd1, wd2;
      split16(__fadd_rn(__fmul_rn(aa, d3), __fmul_rn(ssv, z3a)), h_, l_); wa0 = pack2(h_, l_);
      split16(__fadd_rn(__fmul_rn(aa, d4), __fmul_rn(ssv, z4a)), h_, l_); wa1 = pack2(h_, l_);
      split16(__fadd_rn(__fmul_rn(aa, d5), __fmul_rn(ssv, z5a)), h_, l_); wa2 = pack2(h_, l_);
      split16(__fadd_rn(__fmul_rn(aa, d3), __fmul_rn(ssv, z3b)), h_, l_); wb0 = pack2(h_, l_);
      split16(__fadd_rn(__fmul_rn(aa, d4), __fmul_rn(ssv, z4b)), h_, l_); wb1 = pack2(h_, l_);
      split16(__fadd_rn(__fmul_rn(aa, d5), __fmul_rn(ssv, z5b)), h_, l_); wb2 = pack2(h_, l_);
      split16(__fadd_rn(__fmul_rn(aa, d3), __fmul_rn(ssv, z3c)), h_, l_); wc0 = pack2(h_, l_);
      split16(__fadd_rn(__fmul_rn(aa, d4), __fmul_rn(ssv, z4c)), h_, l_); wc1 = pack2(h_, l_);
      split16(__fadd_rn(__fmul_rn(aa, d5), __fmul_rn(ssv, z5c)), h_, l_); wc2 = pack2(h_, l_);
      split16(__fadd_rn(__fmul_rn(aa, d3), __fmul_rn(ssv, z3d)), h_, l_); wd0 = pack2(h_, l_);
      split16(__fadd_rn(__fmul_rn(aa, d4), __fmul_rn(ssv, z4d)), h_, l_); wd1 = pack2(h_, l_);
      split16(__fadd_rn(__fmul_rn(aa, d5), __fmul_rn(ssv, z5d)), h_, l_); wd2 = pack2(h_, l_);
      int slot = (int)__builtin_amdgcn_mbcnt_hi(
                   (unsigned)(mask >> 32),
                   __builtin_amdgcn_mbcnt_lo((unsigned)mask, 0u));
      myslot = slot;
      znyS0[wv][slot] = make_uint4(wa0, wa1, wa2, (unsigned)qrow);
      znyS1[wv][slot] = make_uint4(wb0, wb1, wb2, 0u);
      znyS2[wv][slot] = make_uint4(wc0, wc1, wc2, 0u);
      znyS3[wv][slot] = make_uint4(wd0, wd1, wd2, 0u);
    }
    // build bq0..3[k] + dvv0..3[k] for k < nbq from compacted slots
    half8 bq0[4], bq1[4], bq2[4], bq3[4];
    float dvv0[4], dvv1[4], dvv2[4], dvv3[4];
#pragma unroll
    for (int k = 0; k < 4; ++k) {
      if (k < nbq) {
        int slot = k * 16 + c15;
        if (slot >= nUnm) slot = 0;        // pad: duplicate slot 0 (unread)
        uint4 za = znyS0[wv][slot];
        uint4 zb = znyS1[wv][slot];
        uint4 zc = znyS2[wv][slot];
        uint4 zd = znyS3[wv][slot];
        int row = (int)za.w;
        int sw = (row >> 2) & 3;
        unsigned sx = 0u, sy = 0u;
        if (quad == 0) {
          uint2 u = *(const uint2*)(stw + row * 8 + 2 * (0 ^ sw));
          sx = u.x; sy = u.y;
        } else if (quad == 1) {
          sx = stw[row * 8 + 2 * (1 ^ sw)];   // data dim 2
        }
        bq0[k] = mk_bq(quad, sx, sy, za.x, za.y, za.z);
        bq1[k] = mk_bq(quad, sx, sy, zb.x, zb.y, zb.z);
        bq2[k] = mk_bq(quad, sx, sy, zc.x, zc.y, zc.z);
        bq3[k] = mk_bq(quad, sx, sy, zd.x, zd.y, zd.z);
        // diag: gathered-A row pair 'quad' of this slot's row, all 4 states
        uint2 u2 = *(const uint2*)(stw + row * 8 + 2 * (quad ^ sw));
        half8 ag = __builtin_bit_cast(half8, make_uint4(u2.x, u2.x, u2.y, u2.y));
        f32x4 z = {0.f, 0.f, 0.f, 0.f};
        f32x4 da = __builtin_amdgcn_mfma_f32_16x16x32_f16(ag, bq0[k], z, 0, 0, 0);
        f32x4 db = __builtin_amdgcn_mfma_f32_16x16x32_f16(ag, bq1[k], z, 0, 0, 0);
        f32x4 dc = __builtin_amdgcn_mfma_f32_16x16x32_f16(ag, bq2[k], z, 0, 0, 0);
        f32x4 dd_ = __builtin_amdgcn_mfma_f32_16x16x32_f16(ag, bq3[k], z, 0, 0, 0);
        int lsrc = ((c15 >> 2) << 4) + c15;
        float d01, d23, dsend;
        d01 = (c15 & 1) ? da[1] : da[0];
        d23 = (c15 & 1) ? da[3] : da[2];
        dsend = (c15 & 2) ? d23 : d01;
        dvv0[k] = __shfl(dsend, lsrc);
        d01 = (c15 & 1) ? db[1] : db[0];
        d23 = (c15 & 1) ? db[3] : db[2];
        dsend = (c15 & 2) ? d23 : d01;
        dvv1[k] = __shfl(dsend, lsrc);
        d01 = (c15 & 1) ? dc[1] : dc[0];
        d23 = (c15 & 1) ? dc[3] : dc[2];
        dsend = (c15 & 2) ? d23 : d01;
        dvv2[k] = __shfl(dsend, lsrc);
        d01 = (c15 & 1) ? dd_[1] : dd_[0];
        d23 = (c15 & 1) ? dd_[3] : dd_[2];
        dsend = (c15 & 2) ? d23 : d01;
        dvv3[k] = __shfl(dsend, lsrc);
      }
    }
    // sweep all 64 candidate tiles at width nbq, 4 states
    float bv0[4], bv1[4], bv2[4], bv3[4];
    switch (nbq) {
      case 1: sweepQ<1>(stw, abase, bq0, bq1, bq2, bq3, bv0, bv1, bv2, bv3); break;
      case 2: sweepQ<2>(stw, abase, bq0, bq1, bq2, bq3, bv0, bv1, bv2, bv3); break;
      case 3: sweepQ<3>(stw, abase, bq0, bq1, bq2, bq3, bv0, bv1, bv2, bv3); break;
      default: sweepQ<4>(stw, abase, bq0, bq1, bq2, bq3, bv0, bv1, bv2, bv3); break;
    }
    // combine quads, compare vs diag -> wave-uniform 16-bit masks per state
    unsigned m0_0 = 0u, m0_1 = 0u, m0_2 = 0u, m0_3 = 0u;
    unsigned m1_0 = 0u, m1_1 = 0u, m1_2 = 0u, m1_3 = 0u;
    unsigned m2_0 = 0u, m2_1 = 0u, m2_2 = 0u, m2_3 = 0u;
    unsigned m3_0 = 0u, m3_1 = 0u, m3_2 = 0u, m3_3 = 0u;
#pragma unroll
    for (int k = 0; k < 4; ++k) {
      if (k < nbq) {
        float v0 = bv0[k];
        v0 = fmaxf(v0, __shfl_xor(v0, 16));
        v0 = fmaxf(v0, __shfl_xor(v0, 32));
        unsigned mA = (unsigned)(__ballot(v0 > dvv0[k]) & 0xffffu);
        float v1 = bv1[k];
        v1 = fmaxf(v1, __shfl_xor(v1, 16));
        v1 = fmaxf(v1, __shfl_xor(v1, 32));
        unsigned mB = (unsigned)(__ballot(v1 > dvv1[k]) & 0xffffu);
        float v2 = bv2[k];
        v2 = fmaxf(v2, __shfl_xor(v2, 16));
        v2 = fmaxf(v2, __shfl_xor(v2, 32));
        unsigned mC = (unsigned)(__ballot(v2 > dvv2[k]) & 0xffffu);
        float v3 = bv3[k];
        v3 = fmaxf(v3, __shfl_xor(v3, 16));
        v3 = fmaxf(v3, __shfl_xor(v3, 32));
        unsigned mD = (unsigned)(__ballot(v3 > dvv3[k]) & 0xffffu);
        if (k == 0) { m0_0 = mA; m1_0 = mB; m2_0 = mC; m3_0 = mD; }
        else if (k == 1) { m0_1 = mA; m1_1 = mB; m2_1 = mC; m3_1 = mD; }
        else if (k == 2) { m0_2 = mA; m1_2 = mB; m2_2 = mC; m3_2 = mD; }
        else { m0_3 = mA; m1_3 = mB; m2_3 = mC; m3_3 = mD; }
      }
    }
    // owner-lane mp update via select tree (no dynamic indexing)
    if (unm) {
      int jt = myslot >> 4, jp = myslot & 15;
      unsigned mA = (jt == 0) ? m0_0 : (jt == 1) ? m0_1
                  : (jt == 2) ? m0_2 : m0_3;
      unsigned mB = (jt == 0) ? m1_0 : (jt == 1) ? m1_1
                  : (jt == 2) ? m1_2 : m1_3;
      unsigned mC = (jt == 0) ? m2_0 : (jt == 1) ? m2_1
                  : (jt == 2) ? m2_2 : m2_3;
      unsigned mD = (jt == 0) ? m3_0 : (jt == 1) ? m3_1
                  : (jt == 2) ? m3_2 : m3_3;
      if (((mA >> jp) & 1u) == 0u) mpv = s0;
      else if (((mB >> jp) & 1u) == 0u) mpv = s0 + 1;
      else if (((mC >> jp) & 1u) == 0u) mpv = s0 + 2;
      else if (((mD >> jp) & 1u) == 0u) mpv = s0 + 3;
    }
  }
  // ---- epilogue: maskg + block cnt -----------------------------------------
  maskg[pg] = (unsigned char)((1u << mpv) - 1u);
#pragma unroll
  for (int k = 0; k < ITERS; ++k) {
    unsigned long long mk = __ballot(mpv > k ? 1 : 0);
    if (lane == 0) atomicAdd(&cnt[k], (unsigned)__popcll(mk));
  }
  __syncthreads();
  if (tid < ITERS) cntg[tid * 512 + (int)blockIdx.x] = cnt[tid];
}

// ---- kernel 3: MLP + masked SE + fused final reduce ------------------------
__global__ __launch_bounds__(256) void k_loss(
    const float* __restrict__ data, const float* __restrict__ noise0,
    const int* __restrict__ ts, const float* __restrict__ sacp,
    const float* __restrict__ s1m, const unsigned* __restrict__ keys,
    const unsigned* __restrict__ cntg, const unsigned char* __restrict__ maskg,
    const float* __restrict__ biasb,
    const float4* __restrict__ PA, const float4* __restrict__ PB,
    const float* __restrict__ PC, const float* __restrict__ b2,
    float* __restrict__ part, unsigned* __restrict__ done,
    float* __restrict__ out) {
  __shared__ float4 sA[HID];
  __shared__ float4 sB[HID];
  __shared__ float2 sCb[HID];
  __shared__ float zn[256][6];     // z3..z5, noisy3..5 per local point
  __shared__ float pp[4][3][256];  // per-wave partials
  __shared__ float red[4];
  __shared__ int ksh;
  __shared__ int lastsh;
  int b = blockIdx.x >> 2, qq = blockIdx.x & 3;
  int tid = (int)threadIdx.x;
  int wv = tid >> 6, lane = tid & 63;
  // ---- phase 1: kstar from cntg --------------------------------------------
  if (tid < 64) {
    int ks = ITERS;
    for (int k2 = 0; k2 < ITERS; ++k2) {
      unsigned v = 0u;
#pragma unroll
      for (int i = 0; i < 8; ++i) v += cntg[k2 * 512 + i * 64 + tid];
#pragma unroll
      for (int m = 32; m >= 1; m >>= 1) v += (unsigned)__shfl_xor((int)v, m);
      if (v < 10u && ks == ITERS) ks = k2;  // first failing iteration
    }
    if (tid == 0) ksh = ks;
  }
  // stage weights meanwhile
  for (int j = tid; j < HID; j += 256) {
    sA[j] = PA[j]; sB[j] = PB[j];
    sCb[j] = make_float2(PC[j], biasb[(size_t)b * HID + j]);
  }
  __syncthreads();
  // ---- phase 2: finalize this block's 256 points (1 per thread) ------------
  int p0 = (b << 10) + qq * 256;
  {
    int kstar = ksh;
    unsigned gate = (kstar >= ITERS) ? 0xFFu : ((1u << kstar) - 1u);
    int p = p0 + tid;
    int t = ts[b];
    float aa = sacp[t], ssv = s1m[t];
    unsigned m = (unsigned)maskg[p] & gate;
    float z3, z4, z5;
    if (m) {
      int j = 31 - __clz((int)m);  // last applied renoise iteration
      unsigned base6 = (unsigned)p * 6u;
      unsigned kk0 = keys[2*j], kk1 = keys[2*j+1];
      z3 = nrm_from_idx(kk0, kk1, base6 + 3u);
      z4 = nrm_from_idx(kk0, kk1, base6 + 4u);
      z5 = nrm_from_idx(kk0, kk1, base6 + 5u);
    } else {
      const float* np0 = noise0 + (size_t)p * 6;
      z3 = np0[3]; z4 = np0[4]; z5 = np0[5];
    }
    const float* dp = data + (size_t)p * 6;
    zn[tid][0] = z3; zn[tid][1] = z4; zn[tid][2] = z5;
    zn[tid][3] = __fadd_rn(__fmul_rn(aa, dp[3]), __fmul_rn(ssv, z3));
    zn[tid][4] = __fadd_rn(__fmul_rn(aa, dp[4]), __fmul_rn(ssv, z4));
    zn[tid][5] = __fadd_rn(__fmul_rn(aa, dp[5]), __fmul_rn(ssv, z5));
  }
  __syncthreads();
  // ---- phase 3: MLP, j-loop split across the 4 waves -----------------------
  float x[4][6];
  float a0[4], a1[4], a2[4];
#pragma unroll
  for (int q = 0; q < 4; ++q) {
    int pl = q * 64 + lane;
    int p = p0 + pl;
    x[q][0] = data[p*6+0]; x[q][1] = data[p*6+1]; x[q][2] = data[p*6+2];
    x[q][3] = zn[pl][3]; x[q][4] = zn[pl][4]; x[q][5] = zn[pl][5];
    a0[q] = 0.f; a1[q] = 0.f; a2[q] = 0.f;
  }
  int j0 = wv * 128;
#pragma unroll 2
  for (int jj = 0; jj < 128; ++jj) {
    int j = j0 + jj;
    float4 A = sA[j];
    float4 Bv = sB[j];
    float2 Cb = sCb[j];
#pragma unroll
    for (int q = 0; q < 4; ++q) {
      float s = x[q][0] * A.x;
      s = fmaf(x[q][1], A.y, s); s = fmaf(x[q][2], A.z, s);
      s = fmaf(x[q][3], A.w, s); s = fmaf(x[q][4], Bv.x, s);
      s = fmaf(x[q][5], Bv.y, s);
      s += Cb.y;
      float h = ftanh(s);
      a0[q] = fmaf(h, Bv.z, a0[q]);
      a1[q] = fmaf(h, Bv.w, a1[q]);
      a2[q] = fmaf(h, Cb.x, a2[q]);
    }
  }
#pragma unroll
  for (int q = 0; q < 4; ++q) {
    pp[wv][0][q * 64 + lane] = a0[q];
    pp[wv][1][q * 64 + lane] = a1[q];
    pp[wv][2][q * 64 + lane] = a2[q];
  }
  __syncthreads();
  float f0 = (pp[0][0][tid] + pp[1][0][tid] + pp[2][0][tid] + pp[3][0][tid])
             + b2[3] - zn[tid][0];
  float f1 = (pp[0][1][tid] + pp[1][1][tid] + pp[2][1][tid] + pp[3][1][tid])
             + b2[4] - zn[tid][1];
  float f2 = (pp[0][2][tid] + pp[1][2][tid] + pp[2][2][tid] + pp[3][2][tid])
             + b2[5] - zn[tid][2];
  float lsum = f0 * f0;
  lsum = fmaf(f1, f1, lsum);
  lsum = fmaf(f2, f2, lsum);
#pragma unroll
  for (int off = 32; off > 0; off >>= 1) lsum += __shfl_down(lsum, off);
  if ((tid & 63) == 0) red[tid >> 6] = lsum;
  __syncthreads();
  // ---- fused final reduce (last-block pattern, bit-identical to k_red) -----
  if (tid == 0) {
    float total = red[0] + red[1] + red[2] + red[3];
    atomicExch(&part[blockIdx.x], total);   // device-scope coherent store
    __threadfence();
    unsigned old = atomicAdd(done, 1u);
    lastsh = (old == 511u) ? 1 : 0;
  }
  __syncthreads();
  if (lastsh && tid < BS) {
    __threadfence();
    float s0 = atomicAdd(&part[4*tid+0], 0.0f);  // device-scope coherent read
    float s1 = atomicAdd(&part[4*tid+1], 0.0f);
    float s2 = atomicAdd(&part[4*tid+2], 0.0f);
    float s3 = atomicAdd(&part[4*tid+3], 0.0f);
    out[tid] = (s0 + s1 + s2 + s3) / 3072.0f;   // same order as old k_red
  }
}

// ---------------------------------------------------------------------------
extern "C" void kernel_launch(void* const* d_in, const int* in_sizes, int n_in,
                              void* d_out, int out_size, void* d_ws, size_t ws_size,
                              hipStream_t stream) {
  (void)in_sizes; (void)n_in; (void)out_size; (void)ws_size;
  const float* data    = (const float*)d_in[0];
  const float* context = (const float*)d_in[1];
  const float* noise0  = (const float*)d_in[2];
  const float* W1      = (const float*)d_in[3];
  const float* Wc      = (const float*)d_in[4];
  const float* Wt      = (const float*)d_in[5];
  const float* b1      = (const float*)d_in[6];
  const float* W2      = (const float*)d_in[7];
  const float* b2      = (const float*)d_in[8];
  const int*   ts      = (const int*)d_in[9];
  float* out = (float*)d_out;

  char* w = (char*)d_ws;
  float*    sacp   = (float*)(w + OFF_SACP);
  float*    s1m    = (float*)(w + OFF_S1M);
  unsigned* keys   = (unsigned*)(w + OFF_KEYS);
  unsigned* cntg   = (unsigned*)(w + OFF_CNTG);
  unsigned* done   = (unsigned*)(w + OFF_DONE);
  unsigned char* maskg = (unsigned char*)(w + OFF_MASK);
  float*    biasb  = (float*)(w + OFF_BIAS);
  float4*   PA     = (float4*)(w + OFF_PA);
  float4*   PB     = (float4*)(w + OFF_PB);
  float*    PC     = (float*)(w + OFF_PC);
  float*    part   = (float*)(w + OFF_PART);

  k_setup<<<258, 256, 0, stream>>>(context, Wc, Wt, b1, ts, biasb,
                                   W1, W2, PA, PB, PC, sacp, s1m, keys, done);
  k_renoise<<<512, 256, 0, stream>>>(data, noise0, ts, sacp, s1m, keys,
                                     cntg, maskg);
  k_loss<<<512, 256, 0, stream>>>(data, noise0, ts, sacp, s1m, keys, cntg,
                                  maskg, biasb, PA, PB, PC, b2, part, done,
                                  out);
}

// Round 14
// 174.815 us; speedup vs baseline: 2.9904x; 2.9904x over previous
//
#include <hip/hip_runtime.h>
#include <hip/hip_bf16.h>
#include <hip/hip_fp16.h>
#include <math.h>

// ---------------------------------------------------------------------------
// Diffusion renoise-loop + conditional MLP loss, MI355X (gfx950).
// RNG: threefry_partitionable (bit-exact, absmax 0.0 rounds 1-13, 15-17, 19-23).
// Round 25: REVERT to r21 (session best, 174.9us, round 9). r24's quad-state
// pass spilled (VGPR cap; WRITE 590MB scratch) -- pass-granularity lever is
// exhausted at 2 states/pass (r21 = 124 VGPR, edge of no-spill envelope).
// r23's fused reduce was neutral; keeping the simpler 4-launch structure.
// Wave-autonomous paired-state passes with point compaction; 4 passes
// {2j,2j+1}; ballot+mbcnt compaction; sweepP<nbq>; no barriers in loop.
#define BS   128
#define NS   1024
#define HID  512
#define CTX  128
#define TT   100
#define ITERS 8

// ---- workspace layout (bytes) ---------------------------------------------
constexpr size_t OFF_SACP  = 0;         // 100 f32
constexpr size_t OFF_S1M   = 512;       // 100 f32
constexpr size_t OFF_KEYS  = 1024;      // 16 u32
constexpr size_t OFF_CNTG  = 1152;      // u32[8][512] -> 17536
constexpr size_t OFF_MASK  = 33920;     // u8[131072] -> 164992
constexpr size_t OFF_BIAS  = 262144;    // f32[128*512] -> 524288
constexpr size_t OFF_PA    = 524288;    // float4[512] -> 532480
constexpr size_t OFF_PB    = 532480;    // float4[512] -> 540672
constexpr size_t OFF_PC    = 540672;    // f32[512]   -> 542720
constexpr size_t OFF_PART  = 542720;    // f32[512]   -> 544768 (~0.55 MB)

typedef __attribute__((ext_vector_type(8))) _Float16 half8;
typedef __attribute__((ext_vector_type(4))) float f32x4;

// ---- threefry2x32-20 -------------------------------------------------------
__device__ __forceinline__ unsigned rotl32(unsigned x, int r) {
  return (x << r) | (x >> (32 - r));
}
__device__ __forceinline__ void tf2x32(unsigned k0, unsigned k1,
                                       unsigned x0, unsigned x1,
                                       unsigned& o0, unsigned& o1) {
  unsigned k2 = k0 ^ k1 ^ 0x1BD11BDAu;
  x0 += k0; x1 += k1;
#define TF_R4(a,b,c,d) \
  x0 += x1; x1 = rotl32(x1,(a)); x1 ^= x0; \
  x0 += x1; x1 = rotl32(x1,(b)); x1 ^= x0; \
  x0 += x1; x1 = rotl32(x1,(c)); x1 ^= x0; \
  x0 += x1; x1 = rotl32(x1,(d)); x1 ^= x0;
  TF_R4(13,15,26,6)   x0 += k1; x1 += k2 + 1u;
  TF_R4(17,29,16,24)  x0 += k2; x1 += k0 + 2u;
  TF_R4(13,15,26,6)   x0 += k0; x1 += k1 + 3u;
  TF_R4(17,29,16,24)  x0 += k1; x1 += k2 + 4u;
  TF_R4(13,15,26,6)   x0 += k2; x1 += k0 + 5u;
#undef TF_R4
  o0 = x0; o1 = x1;
}

__device__ __forceinline__ float bits_to_u(unsigned bits) {
  float f = __uint_as_float((bits >> 9) | 0x3f800000u) - 1.0f;
  float u = f * 2.0f + (-0.99999994f);
  return fmaxf(-0.99999994f, u);
}

__device__ __forceinline__ float nrm_from_idx(unsigned k0, unsigned k1, unsigned idx) {
  unsigned o0, o1;
  tf2x32(k0, k1, 0u, idx, o0, o1);
  return 1.41421356f * erfinvf(bits_to_u(o0 ^ o1));
}

__device__ __forceinline__ float ftanh(float x) {
  float e = __expf(2.0f * x);
  float r = __builtin_amdgcn_rcpf(e + 1.0f);
  return fmaf(-2.0f, r, 1.0f);
}

// fp16 hi/lo split: x ~= hi + lo with |err| <~ 2^-23 |x|
__device__ __forceinline__ void split16(float x, unsigned short& hi, unsigned short& lo) {
  __half h = __float2half(x);
  float hf = __half2float(h);
  __half l = __float2half(x - hf);
  hi = __half_as_ushort(h);
  lo = __half_as_ushort(l);
}
__device__ __forceinline__ unsigned pack2(unsigned short a, unsigned short b) {
  return (unsigned)a | ((unsigned)b << 16);
}
// duplicate low/high 16-bit half of u into both halves (1 v_perm_b32 each)
__device__ __forceinline__ unsigned dup_lo(unsigned u) {
  return __builtin_amdgcn_perm(u, u, 0x01000100u);  // bytes [0,1,0,1]
}
__device__ __forceinline__ unsigned dup_hi(unsigned u) {
  return __builtin_amdgcn_perm(u, u, 0x03020302u);  // bytes [2,3,2,3]
}

// ---- paired-state candidate sweep: NBQ tiles x 2 states over 64 cand tiles -
template<int NBQ>
__device__ __forceinline__ void sweepP(const unsigned* stw, int abase,
                                       const half8* bq0, const half8* bq1,
                                       float* bv0, float* bv1) {
#pragma unroll
  for (int k = 0; k < NBQ; ++k) {
    bv0[k] = -__builtin_inff();
    bv1[k] = -__builtin_inff();
  }
  uint2 cu[4], cun[4];
#pragma unroll
  for (int cc = 0; cc < 4; ++cc)
    cu[cc] = *(const uint2*)(stw + cc * 128 + abase);
#pragma unroll 1
  for (int ctc = 0; ctc < 16; ++ctc) {
    if (ctc < 15) {
#pragma unroll
      for (int cc = 0; cc < 4; ++cc)
        cun[cc] = *(const uint2*)(stw + ((ctc + 1) * 4 + cc) * 128 + abase);
    }
#pragma unroll
    for (int cc = 0; cc < 4; ++cc) {
      half8 ac = __builtin_bit_cast(half8,
                   make_uint4(cu[cc].x, cu[cc].x, cu[cc].y, cu[cc].y));
      f32x4 z = {0.f, 0.f, 0.f, 0.f};
#pragma unroll
      for (int k = 0; k < NBQ; ++k) {
        f32x4 a = __builtin_amdgcn_mfma_f32_16x16x32_f16(ac, bq0[k], z, 0, 0, 0);
        f32x4 a2 = __builtin_amdgcn_mfma_f32_16x16x32_f16(ac, bq1[k], z, 0, 0, 0);
        bv0[k] = fmaxf(fmaxf(bv0[k], fmaxf(fmaxf(a[0], a[1]), a[2])), a[3]);
        bv1[k] = fmaxf(fmaxf(bv1[k], fmaxf(fmaxf(a2[0], a2[1]), a2[2])), a2[3]);
      }
    }
    if (ctc < 15) {
#pragma unroll
      for (int cc = 0; cc < 4; ++cc) cu[cc] = cun[cc];
    }
  }
}

// ---- kernel 1: setup — blocks 0..255 bias, 256 weight pack, 257 tables -----
__global__ __launch_bounds__(256) void k_setup(
    const float* __restrict__ ctx, const float* __restrict__ Wc,
    const float* __restrict__ Wt, const float* __restrict__ b1,
    const int* __restrict__ ts, float* __restrict__ biasb,
    const float* __restrict__ W1, const float* __restrict__ W2,
    float4* __restrict__ PA, float4* __restrict__ PB, float* __restrict__ PC,
    float* __restrict__ sacp, float* __restrict__ s1m,
    unsigned* __restrict__ keys) {
  if (blockIdx.x == 257) {
    __shared__ double omb[TT];
    int t = threadIdx.x;
    if (t < TT) {
      const double PI = 3.14159265358979323846;
      double t0 = (double)t / TT, t1 = (double)(t + 1) / TT;
      double c0 = cos((t0 + 0.008) / 1.008 * PI * 0.5); double ab0 = c0 * c0;
      double c1 = cos((t1 + 0.008) / 1.008 * PI * 0.5); double ab1 = c1 * c1;
      double beta = 1.0 - ab1 / ab0;
      if (beta > 0.999) beta = 0.999;
      omb[t] = 1.0 - beta;
    }
    __syncthreads();
    if (t < TT) {
      double acp = 1.0;
      for (int i = 0; i <= t; ++i) acp *= omb[i];
      sacp[t] = (float)sqrt(acp);
      s1m[t]  = (float)sqrt(1.0 - acp);
    }
    if (t >= 128 && t < 128 + ITERS) {
      int k = t - 128;
      unsigned o0, o1;
      tf2x32(0u, 42u, 0u, (unsigned)k, o0, o1);
      keys[2*k] = o0; keys[2*k+1] = o1;
    }
    return;
  }
  if (blockIdx.x == 256) {
    for (int j = threadIdx.x; j < HID; j += 256) {
      PA[j] = make_float4(W1[j], W1[512 + j], W1[1024 + j], W1[1536 + j]);
      PB[j] = make_float4(W1[2048 + j], W1[2560 + j], W2[j*6 + 3], W2[j*6 + 4]);
      PC[j] = W2[j*6 + 5];
    }
    return;
  }
  __shared__ float sc[CTX];
  int b = blockIdx.x >> 1;
  int j = (blockIdx.x & 1) * 256 + (int)threadIdx.x;
  if (threadIdx.x < CTX) sc[threadIdx.x] = ctx[(size_t)b * CTX + threadIdx.x];
  __syncthreads();
  float acc = 0.f;
  for (int q = 0; q < CTX; ++q) acc = fmaf(sc[q], Wc[q * HID + j], acc);
  float temb = (float)ts[b] / 100.0f;
  biasb[b * HID + j] = acc + temb * Wt[j] + b1[j];
}

// ---- kernel 2: renoise — 512 blocks (4 q-slices x 128 batches) -------------
// Wave-autonomous paired-state passes with point compaction. Wave owns 64
// queries; per pass j (states 2j,2j+1): ballot+mbcnt compacts unmatched into
// znyS0/znyS1 slots; nbq=ceil(nUnm/16) tiles; sweepP<nbq> evaluates both
// states; mp = s0 if s0-bit clear else s1 if s1-bit clear. No barriers in
// the loop; wave exits when all its points matched.
__global__ __launch_bounds__(256, 2) void k_renoise(
    const float* __restrict__ data, const float* __restrict__ noise0,
    const int* __restrict__ ts, const float* __restrict__ sacp,
    const float* __restrict__ s1m, const unsigned* __restrict__ keys,
    unsigned* __restrict__ cntg, unsigned char* __restrict__ maskg) {
  __shared__ unsigned stw[8192];           // 32 KB: 1024 rec x 8 words (r17)
  __shared__ uint4 znyS0[4][64];           // 4 KB: [wave][slot] s0 words+row
  __shared__ uint4 znyS1[4][64];           // 4 KB: [wave][slot] s1 words
  __shared__ unsigned cnt[8];
  const int b = blockIdx.x & 127, qb = blockIdx.x >> 7;  // qb 0..3
  const int tid = (int)threadIdx.x;
  const int wv = tid >> 6, lane = tid & 63;
  const int c15 = lane & 15, quad = lane >> 4;
  const int n0 = qb * 256;
  const int t = ts[b];
  const float aa = sacp[t], ssv = s1m[t];
  if (tid < ITERS) cnt[tid] = 0u;
  // ---- stage full panel: 4 rows/thread, swizzled pair stores (r17) ---------
#pragma unroll 1
  for (int ii = 0; ii < 4; ++ii) {
    int c = ii * 256 + tid;
    const float2* dp2 = (const float2*)(data + ((size_t)(b << 10) + c) * 6);
    float2 v0 = dp2[0], v1 = dp2[1], v2 = dp2[2];
    float dd[6] = {v0.x, v0.y, v1.x, v1.y, v2.x, v2.y};
    float dsq = dd[0]*dd[0];
    dsq = fmaf(dd[1], dd[1], dsq); dsq = fmaf(dd[2], dd[2], dsq);
    dsq = fmaf(dd[3], dd[3], dsq); dsq = fmaf(dd[4], dd[4], dsq);
    dsq = fmaf(dd[5], dd[5], dsq);
    unsigned U[6];
#pragma unroll
    for (int d = 0; d < 6; ++d) {
      unsigned short hi, lo; split16(dd[d], hi, lo);
      U[d] = pack2(hi, lo);
    }
    unsigned short vh, vl; split16(-0.5f * dsq, vh, vl);
    int sc_ = (c >> 2) & 3;
    unsigned* rec = stw + c * 8;
    *(uint2*)(rec + 2 * (0 ^ sc_)) = make_uint2(U[0], U[1]);
    *(uint2*)(rec + 2 * (1 ^ sc_)) = make_uint2(U[2], U[3]);
    *(uint2*)(rec + 2 * (2 ^ sc_)) = make_uint2(U[4], U[5]);
    *(uint2*)(rec + 2 * (3 ^ sc_)) = make_uint2(pack2(vh, vl), 0u);
  }
  // candidate A-gather base: rows cc*16+c15 -> (row>>2)&3 == c15>>2
  const int abase = c15 * 8 + 2 * (quad ^ (c15 >> 2));
  __syncthreads();
  // ---- per-lane persistent state -------------------------------------------
  const int qrow = n0 + wv * 64 + lane;    // row within batch panel (0..1023)
  const int pg = (b << 10) + qrow;         // global point index
  const float* dpq = data + (size_t)pg * 6;
  const float d3 = dpq[3], d4 = dpq[4], d5 = dpq[5];
  int mpv = 8;
  int myslot = 0;
  // ---- wave-autonomous paired-state passes ---------------------------------
#pragma unroll 1
  for (int j = 0; j < 4; ++j) {
    const int s0 = 2 * j;
    bool unm = (mpv == 8);
    unsigned long long mask = __ballot(unm ? 1 : 0);
    if (mask == 0ull) break;               // wave done; SIMD freed
    int nUnm = (int)__popcll(mask);
    int nbq = (nUnm + 15) >> 4;            // 1..4 query tiles
    if (unm) {
      unsigned base6 = (unsigned)pg * 6u;
      float z3a, z4a, z5a;
      if (j == 0) {
        const float* np0 = noise0 + (size_t)pg * 6;
        z3a = np0[3]; z4a = np0[4]; z5a = np0[5];
      } else {
        unsigned ka0 = keys[2*(s0-1)], ka1 = keys[2*(s0-1)+1];
        z3a = nrm_from_idx(ka0, ka1, base6 + 3u);
        z4a = nrm_from_idx(ka0, ka1, base6 + 4u);
        z5a = nrm_from_idx(ka0, ka1, base6 + 5u);
      }
      unsigned kb0 = keys[2*s0], kb1 = keys[2*s0+1];
      float z3b = nrm_from_idx(kb0, kb1, base6 + 3u);
      float z4b = nrm_from_idx(kb0, kb1, base6 + 4u);
      float z5b = nrm_from_idx(kb0, kb1, base6 + 5u);
      float v3a = __fadd_rn(__fmul_rn(aa, d3), __fmul_rn(ssv, z3a));
      float v4a = __fadd_rn(__fmul_rn(aa, d4), __fmul_rn(ssv, z4a));
      float v5a = __fadd_rn(__fmul_rn(aa, d5), __fmul_rn(ssv, z5a));
      float v3b = __fadd_rn(__fmul_rn(aa, d3), __fmul_rn(ssv, z3b));
      float v4b = __fadd_rn(__fmul_rn(aa, d4), __fmul_rn(ssv, z4b));
      float v5b = __fadd_rn(__fmul_rn(aa, d5), __fmul_rn(ssv, z5b));
      unsigned short h_, l_;
      unsigned w0a, w1a, w2a, w0b, w1b, w2b;
      split16(v3a, h_, l_); w0a = pack2(h_, l_);
      split16(v4a, h_, l_); w1a = pack2(h_, l_);
      split16(v5a, h_, l_); w2a = pack2(h_, l_);
      split16(v3b, h_, l_); w0b = pack2(h_, l_);
      split16(v4b, h_, l_); w1b = pack2(h_, l_);
      split16(v5b, h_, l_); w2b = pack2(h_, l_);
      int slot = (int)__builtin_amdgcn_mbcnt_hi(
                   (unsigned)(mask >> 32),
                   __builtin_amdgcn_mbcnt_lo((unsigned)mask, 0u));
      myslot = slot;
      znyS0[wv][slot] = make_uint4(w0a, w1a, w2a, (unsigned)qrow);
      znyS1[wv][slot] = make_uint4(w0b, w1b, w2b, 0u);
    }
    // build bq0/bq1[k] + dvv0/dvv1[k] for k < nbq from compacted slots
    half8 bq0[4], bq1[4];
    float dvv0[4], dvv1[4];
#pragma unroll
    for (int k = 0; k < 4; ++k) {
      if (k < nbq) {
        int slot = k * 16 + c15;
        if (slot >= nUnm) slot = 0;        // pad: duplicate slot 0 (unread)
        uint4 za = znyS0[wv][slot];
        uint4 zb = znyS1[wv][slot];
        int row = (int)za.w;
        int sw = (row >> 2) & 3;
        uint4 wa = make_uint4(0u, 0u, 0u, 0u);
        uint4 wb = make_uint4(0u, 0u, 0u, 0u);
        if (quad == 0) {
          uint2 u = *(const uint2*)(stw + row * 8 + 2 * (0 ^ sw));
          wa.x = dup_lo(u.x); wa.y = dup_hi(u.x);
          wa.z = dup_lo(u.y); wa.w = dup_hi(u.y);
          wb = wa;
        } else if (quad == 1) {
          unsigned ud = stw[row * 8 + 2 * (1 ^ sw)];   // dim 2
          wa.x = dup_lo(ud); wa.y = dup_hi(ud);
          wa.z = dup_lo(za.x); wa.w = dup_hi(za.x);
          wb.x = wa.x; wb.y = wa.y;
          wb.z = dup_lo(zb.x); wb.w = dup_hi(zb.x);
        } else if (quad == 2) {
          wa.x = dup_lo(za.y); wa.y = dup_hi(za.y);
          wa.z = dup_lo(za.z); wa.w = dup_hi(za.z);
          wb.x = dup_lo(zb.y); wb.y = dup_hi(zb.y);
          wb.z = dup_lo(zb.z); wb.w = dup_hi(zb.z);
        } else {
          wa.x = 0x3C003C00u;
          wb = wa;
        }
        bq0[k] = __builtin_bit_cast(half8, wa);
        bq1[k] = __builtin_bit_cast(half8, wb);
        // diag: gathered-A row pair 'quad' of this slot's row, both states
        uint2 u2 = *(const uint2*)(stw + row * 8 + 2 * (quad ^ sw));
        half8 ag = __builtin_bit_cast(half8, make_uint4(u2.x, u2.x, u2.y, u2.y));
        f32x4 z = {0.f, 0.f, 0.f, 0.f};
        f32x4 da = __builtin_amdgcn_mfma_f32_16x16x32_f16(ag, bq0[k], z, 0, 0, 0);
        f32x4 db = __builtin_amdgcn_mfma_f32_16x16x32_f16(ag, bq1[k], z, 0, 0, 0);
        float d01 = (c15 & 1) ? da[1] : da[0];
        float d23 = (c15 & 1) ? da[3] : da[2];
        float dsend = (c15 & 2) ? d23 : d01;
        dvv0[k] = __shfl(dsend, ((c15 >> 2) << 4) + c15);
        d01 = (c15 & 1) ? db[1] : db[0];
        d23 = (c15 & 1) ? db[3] : db[2];
        dsend = (c15 & 2) ? d23 : d01;
        dvv1[k] = __shfl(dsend, ((c15 >> 2) << 4) + c15);
      }
    }
    // sweep all 64 candidate tiles at width nbq, both states
    float bv0[4], bv1[4];
    switch (nbq) {
      case 1: sweepP<1>(stw, abase, bq0, bq1, bv0, bv1); break;
      case 2: sweepP<2>(stw, abase, bq0, bq1, bv0, bv1); break;
      case 3: sweepP<3>(stw, abase, bq0, bq1, bv0, bv1); break;
      default: sweepP<4>(stw, abase, bq0, bq1, bv0, bv1); break;
    }
    // combine quads, compare vs diag -> wave-uniform 16-bit masks per state
    unsigned m0_0 = 0u, m0_1 = 0u, m0_2 = 0u, m0_3 = 0u;
    unsigned m1_0 = 0u, m1_1 = 0u, m1_2 = 0u, m1_3 = 0u;
#pragma unroll
    for (int k = 0; k < 4; ++k) {
      if (k < nbq) {
        float v = bv0[k];
        v = fmaxf(v, __shfl_xor(v, 16));
        v = fmaxf(v, __shfl_xor(v, 32));
        unsigned mA = (unsigned)(__ballot(v > dvv0[k]) & 0xffffu);
        float w = bv1[k];
        w = fmaxf(w, __shfl_xor(w, 16));
        w = fmaxf(w, __shfl_xor(w, 32));
        unsigned mB = (unsigned)(__ballot(w > dvv1[k]) & 0xffffu);
        if (k == 0) { m0_0 = mA; m1_0 = mB; }
        else if (k == 1) { m0_1 = mA; m1_1 = mB; }
        else if (k == 2) { m0_2 = mA; m1_2 = mB; }
        else { m0_3 = mA; m1_3 = mB; }
      }
    }
    // owner-lane mp update via select tree (no dynamic indexing)
    if (unm) {
      int jt = myslot >> 4, jp = myslot & 15;
      unsigned mA = (jt == 0) ? m0_0 : (jt == 1) ? m0_1
                  : (jt == 2) ? m0_2 : m0_3;
      unsigned mB = (jt == 0) ? m1_0 : (jt == 1) ? m1_1
                  : (jt == 2) ? m1_2 : m1_3;
      if (((mA >> jp) & 1u) == 0u) mpv = s0;
      else if (((mB >> jp) & 1u) == 0u) mpv = s0 + 1;
    }
  }
  // ---- epilogue: maskg + block cnt -----------------------------------------
  maskg[pg] = (unsigned char)((1u << mpv) - 1u);
#pragma unroll
  for (int k = 0; k < ITERS; ++k) {
    unsigned long long mk = __ballot(mpv > k ? 1 : 0);
    if (lane == 0) atomicAdd(&cnt[k], (unsigned)__popcll(mk));
  }
  __syncthreads();
  if (tid < ITERS) cntg[tid * 512 + (int)blockIdx.x] = cnt[tid];
}

// ---- kernel 3: MLP + masked SE, with fused finalize (exact cont gate) ------
__global__ __launch_bounds__(256) void k_loss(
    const float* __restrict__ data, const float* __restrict__ noise0,
    const int* __restrict__ ts, const float* __restrict__ sacp,
    const float* __restrict__ s1m, const unsigned* __restrict__ keys,
    const unsigned* __restrict__ cntg, const unsigned char* __restrict__ maskg,
    const float* __restrict__ biasb,
    const float4* __restrict__ PA, const float4* __restrict__ PB,
    const float* __restrict__ PC, const float* __restrict__ b2,
    float* __restrict__ part) {
  __shared__ float4 sA[HID];
  __shared__ float4 sB[HID];
  __shared__ float2 sCb[HID];
  __shared__ float zn[256][6];     // z3..z5, noisy3..5 per local point
  __shared__ float pp[4][3][256];  // per-wave partials
  __shared__ float red[4];
  __shared__ int ksh;
  int b = blockIdx.x >> 2, qq = blockIdx.x & 3;
  int tid = (int)threadIdx.x;
  int wv = tid >> 6, lane = tid & 63;
  // ---- phase 1: kstar from cntg --------------------------------------------
  if (tid < 64) {
    int ks = ITERS;
    for (int k2 = 0; k2 < ITERS; ++k2) {
      unsigned v = 0u;
#pragma unroll
      for (int i = 0; i < 8; ++i) v += cntg[k2 * 512 + i * 64 + tid];
#pragma unroll
      for (int m = 32; m >= 1; m >>= 1) v += (unsigned)__shfl_xor((int)v, m);
      if (v < 10u && ks == ITERS) ks = k2;  // first failing iteration
    }
    if (tid == 0) ksh = ks;
  }
  // stage weights meanwhile
  for (int j = tid; j < HID; j += 256) {
    sA[j] = PA[j]; sB[j] = PB[j];
    sCb[j] = make_float2(PC[j], biasb[(size_t)b * HID + j]);
  }
  __syncthreads();
  // ---- phase 2: finalize this block's 256 points (1 per thread) ------------
  int p0 = (b << 10) + qq * 256;
  {
    int kstar = ksh;
    unsigned gate = (kstar >= ITERS) ? 0xFFu : ((1u << kstar) - 1u);
    int p = p0 + tid;
    int t = ts[b];
    float aa = sacp[t], ssv = s1m[t];
    unsigned m = (unsigned)maskg[p] & gate;
    float z3, z4, z5;
    if (m) {
      int j = 31 - __clz((int)m);  // last applied renoise iteration
      unsigned base6 = (unsigned)p * 6u;
      unsigned kk0 = keys[2*j], kk1 = keys[2*j+1];
      z3 = nrm_from_idx(kk0, kk1, base6 + 3u);
      z4 = nrm_from_idx(kk0, kk1, base6 + 4u);
      z5 = nrm_from_idx(kk0, kk1, base6 + 5u);
    } else {
      const float* np0 = noise0 + (size_t)p * 6;
      z3 = np0[3]; z4 = np0[4]; z5 = np0[5];
    }
    const float* dp = data + (size_t)p * 6;
    zn[tid][0] = z3; zn[tid][1] = z4; zn[tid][2] = z5;
    zn[tid][3] = __fadd_rn(__fmul_rn(aa, dp[3]), __fmul_rn(ssv, z3));
    zn[tid][4] = __fadd_rn(__fmul_rn(aa, dp[4]), __fmul_rn(ssv, z4));
    zn[tid][5] = __fadd_rn(__fmul_rn(aa, dp[5]), __fmul_rn(ssv, z5));
  }
  __syncthreads();
  // ---- phase 3: MLP, j-loop split across the 4 waves -----------------------
  float x[4][6];
  float a0[4], a1[4], a2[4];
#pragma unroll
  for (int q = 0; q < 4; ++q) {
    int pl = q * 64 + lane;
    int p = p0 + pl;
    x[q][0] = data[p*6+0]; x[q][1] = data[p*6+1]; x[q][2] = data[p*6+2];
    x[q][3] = zn[pl][3]; x[q][4] = zn[pl][4]; x[q][5] = zn[pl][5];
    a0[q] = 0.f; a1[q] = 0.f; a2[q] = 0.f;
  }
  int j0 = wv * 128;
#pragma unroll 2
  for (int jj = 0; jj < 128; ++jj) {
    int j = j0 + jj;
    float4 A = sA[j];
    float4 Bv = sB[j];
    float2 Cb = sCb[j];
#pragma unroll
    for (int q = 0; q < 4; ++q) {
      float s = x[q][0] * A.x;
      s = fmaf(x[q][1], A.y, s); s = fmaf(x[q][2], A.z, s);
      s = fmaf(x[q][3], A.w, s); s = fmaf(x[q][4], Bv.x, s);
      s = fmaf(x[q][5], Bv.y, s);
      s += Cb.y;
      float h = ftanh(s);
      a0[q] = fmaf(h, Bv.z, a0[q]);
      a1[q] = fmaf(h, Bv.w, a1[q]);
      a2[q] = fmaf(h, Cb.x, a2[q]);
    }
  }
#pragma unroll
  for (int q = 0; q < 4; ++q) {
    pp[wv][0][q * 64 + lane] = a0[q];
    pp[wv][1][q * 64 + lane] = a1[q];
    pp[wv][2][q * 64 + lane] = a2[q];
  }
  __syncthreads();
  float f0 = (pp[0][0][tid] + pp[1][0][tid] + pp[2][0][tid] + pp[3][0][tid])
             + b2[3] - zn[tid][0];
  float f1 = (pp[0][1][tid] + pp[1][1][tid] + pp[2][1][tid] + pp[3][1][tid])
             + b2[4] - zn[tid][1];
  float f2 = (pp[0][2][tid] + pp[1][2][tid] + pp[2][2][tid] + pp[3][2][tid])
             + b2[5] - zn[tid][2];
  float lsum = f0 * f0;
  lsum = fmaf(f1, f1, lsum);
  lsum = fmaf(f2, f2, lsum);
#pragma unroll
  for (int off = 32; off > 0; off >>= 1) lsum += __shfl_down(lsum, off);
  if ((tid & 63) == 0) red[tid >> 6] = lsum;
  __syncthreads();
  if (tid == 0) part[blockIdx.x] = red[0] + red[1] + red[2] + red[3];
}

// ---- kernel 4: final reduce ------------------------------------------------
__global__ void k_red(const float* __restrict__ part, float* __restrict__ out) {
  int b = (int)threadIdx.x;
  if (b < BS) {
    out[b] = (part[4*b] + part[4*b+1] + part[4*b+2] + part[4*b+3]) / 3072.0f;
  }
}

// ---------------------------------------------------------------------------
extern "C" void kernel_launch(void* const* d_in, const int* in_sizes, int n_in,
                              void* d_out, int out_size, void* d_ws, size_t ws_size,
                              hipStream_t stream) {
  (void)in_sizes; (void)n_in; (void)out_size; (void)ws_size;
  const float* data    = (const float*)d_in[0];
  const float* context = (const float*)d_in[1];
  const float* noise0  = (const float*)d_in[2];
  const float* W1      = (const float*)d_in[3];
  const float* Wc      = (const float*)d_in[4];
  const float* Wt      = (const float*)d_in[5];
  const float* b1      = (const float*)d_in[6];
  const float* W2      = (const float*)d_in[7];
  const float* b2      = (const float*)d_in[8];
  const int*   ts      = (const int*)d_in[9];
  float* out = (float*)d_out;

  char* w = (char*)d_ws;
  float*    sacp   = (float*)(w + OFF_SACP);
  float*    s1m    = (float*)(w + OFF_S1M);
  unsigned* keys   = (unsigned*)(w + OFF_KEYS);
  unsigned* cntg   = (unsigned*)(w + OFF_CNTG);
  unsigned char* maskg = (unsigned char*)(w + OFF_MASK);
  float*    biasb  = (float*)(w + OFF_BIAS);
  float4*   PA     = (float4*)(w + OFF_PA);
  float4*   PB     = (float4*)(w + OFF_PB);
  float*    PC     = (float*)(w + OFF_PC);
  float*    part   = (float*)(w + OFF_PART);

  k_setup<<<258, 256, 0, stream>>>(context, Wc, Wt, b1, ts, biasb,
                                   W1, W2, PA, PB, PC, sacp, s1m, keys);
  k_renoise<<<512, 256, 0, stream>>>(data, noise0, ts, sacp, s1m, keys,
                                     cntg, maskg);
  k_loss<<<512, 256, 0, stream>>>(data, noise0, ts, sacp, s1m, keys, cntg,
                                  maskg, biasb, PA, PB, PC, b2, part);
  k_red<<<1, 128, 0, stream>>>(part, out);
}